// Round 8
// baseline (248.625 us; speedup 1.0000x reference)
//
#include <hip/hip_runtime.h>
#include <hip/hip_bf16.h>

// Problem constants
#define BB 32
#define SS 1024
#define TT 64
#define HD 1024   // 2H
#define FF 2048   // 4H
#define MM (BB*SS) // 32768

typedef __attribute__((ext_vector_type(4))) float f32x4;
typedef __attribute__((ext_vector_type(8))) short bf16x8;
typedef __attribute__((ext_vector_type(8))) unsigned short u16x8;

__device__ __forceinline__ unsigned short f2bf(float f) {
  __hip_bfloat16 h = __float2bfloat16(f);
  return __builtin_bit_cast(unsigned short, h);
}

__device__ __forceinline__ void gll16(const void* g, void* l) {
  __builtin_amdgcn_global_load_lds(
      (const __attribute__((address_space(1))) void*)g,
      (__attribute__((address_space(3))) void*)l, 16, 0, 0);
}

// ---------------------------------------------------------------- converts
__global__ void cvt_bf16_kernel(const float* __restrict__ x,
                                unsigned short* __restrict__ y, int n4) {
  int stride = gridDim.x * blockDim.x;
  for (int i = blockIdx.x * blockDim.x + threadIdx.x; i < n4; i += stride) {
    float4 v = reinterpret_cast<const float4*>(x)[i];
    ushort4 o;
    o.x = f2bf(v.x); o.y = f2bf(v.y); o.z = f2bf(v.z); o.w = f2bf(v.w);
    reinterpret_cast<ushort4*>(y)[i] = o;
  }
}

// transpose+convert: in fp32 [bz][R][C] -> out bf16 [bz][C][R]
__global__ void tcvt_kernel(const float* __restrict__ in,
                            unsigned short* __restrict__ out, int R, int C) {
  __shared__ float tile[32][33];
  const int bz = blockIdx.z;
  const float* ip = in + (size_t)bz * R * C;
  unsigned short* op = out + (size_t)bz * R * C;
  const int c0 = blockIdx.x * 32, r0 = blockIdx.y * 32;
  const int tx = threadIdx.x, ty = threadIdx.y; // (32, 8)
#pragma unroll
  for (int j = 0; j < 4; ++j)
    tile[ty + j * 8][tx] = ip[(size_t)(r0 + ty + j * 8) * C + c0 + tx];
  __syncthreads();
#pragma unroll
  for (int j = 0; j < 4; ++j)
    op[(size_t)(c0 + ty + j * 8) * R + r0 + tx] = f2bf(tile[tx][ty + j * 8]);
}

// ---------------------------------------------------------------- attention
// R8: barrier-free QK^T with per-lane direct fragment loads.
// Lane (lrow,lk) of wave w loads ITS OWN Q-frag from hid fp32 (row w*16+lrow,
// cols kt*32+lk*8 — each element read exactly once), converts in-reg, stores
// the bf16 chunk to hid_bf (side output, exact cover), and feeds the MFMA
// directly. K-frags come per-lane from tgt_bf (4 MB, L2-resident). No LDS,
// no barriers until the single Ps handoff before PV.
__global__ __launch_bounds__(256) void attn_kernel(
    const float* __restrict__ hid_f32,           // [B][S][D] fp32
    unsigned short* __restrict__ hid_bf,         // out: [B][S][D] bf16
    const unsigned short* __restrict__ tgt_bf,   // [B][T][D]
    const unsigned short* __restrict__ tgtT_bf,  // [B][D][T]
    unsigned short* __restrict__ ti_bf)          // [B][S][D]
{
  __shared__ unsigned short Ps[64 * 72];  // pad 64->72 (2-way only)

  const int tid = threadIdx.x;
  const int w = tid >> 6, l = tid & 63;
  const int lrow = l & 15, lk = l >> 4;
  const int b = blockIdx.y;
  const int sbase = blockIdx.x * 64;
  const size_t hbase = ((size_t)b * SS + sbase) * HD;

  const int qrow = w * 16 + lrow;
  const float* qp = hid_f32 + hbase + (size_t)qrow * HD + lk * 8;
  unsigned short* qbf = hid_bf + hbase + (size_t)qrow * HD + lk * 8;
  const unsigned short* kp = tgt_bf + (size_t)b * TT * HD + (size_t)lrow * HD + lk * 8;

  f32x4 accs[4] = {};
  for (int kt = 0; kt < 32; ++kt) {
    const int kk = kt * 32;
    float4 f0 = *reinterpret_cast<const float4*>(qp + kk);
    float4 f1 = *reinterpret_cast<const float4*>(qp + kk + 4);
    bf16x8 a;
    a[0] = (short)f2bf(f0.x); a[1] = (short)f2bf(f0.y);
    a[2] = (short)f2bf(f0.z); a[3] = (short)f2bf(f0.w);
    a[4] = (short)f2bf(f1.x); a[5] = (short)f2bf(f1.y);
    a[6] = (short)f2bf(f1.z); a[7] = (short)f2bf(f1.w);
    *reinterpret_cast<bf16x8*>(qbf + kk) = a;   // hid_bf side output
#pragma unroll
    for (int ct = 0; ct < 4; ++ct) {
      bf16x8 bb = *reinterpret_cast<const bf16x8*>(kp + (size_t)ct * 16 * HD + kk);
      accs[ct] = __builtin_amdgcn_mfma_f32_16x16x32_bf16(a, bb, accs[ct], 0, 0, 0);
    }
  }

  // ---- softmax over t (lane holds q-rows lk*4+j, t-cols ct*16+lrow) ----
  float p[4][4];
#pragma unroll
  for (int j = 0; j < 4; ++j) {
    float mx = fmaxf(fmaxf(accs[0][j], accs[1][j]), fmaxf(accs[2][j], accs[3][j]));
#pragma unroll
    for (int d = 1; d < 16; d <<= 1) mx = fmaxf(mx, __shfl_xor(mx, d, 64));
    float sum = 0.f;
#pragma unroll
    for (int ct = 0; ct < 4; ++ct) { p[ct][j] = __expf(accs[ct][j] - mx); sum += p[ct][j]; }
#pragma unroll
    for (int d = 1; d < 16; d <<= 1) sum += __shfl_xor(sum, d, 64);
    float inv = 1.f / sum;
#pragma unroll
    for (int ct = 0; ct < 4; ++ct) p[ct][j] *= inv;
  }
#pragma unroll
  for (int j = 0; j < 4; ++j)
#pragma unroll
    for (int ct = 0; ct < 4; ++ct)
      Ps[(w * 16 + lk * 4 + j) * 72 + ct * 16 + lrow] = f2bf(p[ct][j]);
  __syncthreads();

  // ---- PV: ti(64x1024) = P(64x64) @ tgt; B-frags from tgtT [D][T] ----
  const size_t tTbase = (size_t)b * HD * TT;
  for (int chunk = 0; chunk < 16; ++chunk) {
    const int colbase = chunk * 64;
    f32x4 acco[4] = {};
#pragma unroll
    for (int kk2 = 0; kk2 < 2; ++kk2) {
      bf16x8 a = *reinterpret_cast<const bf16x8*>(&Ps[(w * 16 + lrow) * 72 + kk2 * 32 + lk * 8]);
#pragma unroll
      for (int ct = 0; ct < 4; ++ct) {
        const unsigned short* gp =
            tgtT_bf + tTbase + (size_t)(colbase + ct * 16 + lrow) * TT + kk2 * 32 + lk * 8;
        bf16x8 bb = *reinterpret_cast<const bf16x8*>(gp);
        acco[ct] = __builtin_amdgcn_mfma_f32_16x16x32_bf16(a, bb, acco[ct], 0, 0, 0);
      }
    }
#pragma unroll
    for (int ct = 0; ct < 4; ++ct)
#pragma unroll
      for (int j = 0; j < 4; ++j)
        ti_bf[hbase + (size_t)(w * 16 + lk * 4 + j) * HD + colbase + ct * 16 + lrow] =
            f2bf(acco[ct][j]);
  }
}

// ---------------------------------------------------------------- transform GEMM
// R7 structure (measured best: 151.5 us, 0 bank conflicts, MfmaUtil 39%):
// 256x256 / BK=64 / 8 waves (2Mx4N) / 16x16x32 MFMA / 4 phase-end barriers
// per tile / 3-bit XOR swizzle / counted vmcnt(4) / compiler lgkm waits.

__global__ __launch_bounds__(512) void gemm_kernel(
    const unsigned short* __restrict__ hid_bf,  // [M][1024]
    const unsigned short* __restrict__ ti_bf,   // [M][1024]
    const unsigned short* __restrict__ Wt_bf,   // [1024][2048]  (n-major)
    const float* __restrict__ bias,             // [1024]
    float* __restrict__ out)                    // [M][1024]
{
  __shared__ unsigned short lds[65536];  // 128 KiB

  const int tid = threadIdx.x;
  const int w = tid >> 6, l = tid & 63;
  const int wm = w >> 2, wn = w & 3;       // 2 x 4 wave grid
  const int lrow = l & 15, lk = l >> 4;

  // XCD-aware bijective swizzle (nwg = 512, divisible by 8)
  const int orig = blockIdx.y * 4 + blockIdx.x;
  const int lid = (orig & 7) * 64 + (orig >> 3);
  const int nbase = (lid & 3) * 256;
  const int mbase = (lid >> 2) * 256;

  // staging lane geometry: row-in-half = rd*64 + srow8; col chunk pre-swizzled
  const int srow8 = w * 8 + (l >> 3);           // 0..63
  const int scol = ((l & 7) ^ (l >> 3)) << 3;   // element col offset (swizzled)

  // ds_read swizzled chunk offsets (elements): chunk (kh*4+lk) ^ (row&7)
  const int ck0 = ((lk)     ^ (lrow & 7)) << 3;
  const int ck1 = ((4 + lk) ^ (lrow & 7)) << 3;

#define STAGE_A(s, bsel, h) do {                                               \
    const int k0_ = (s) * 64;                                                  \
    const unsigned short* p_ = (k0_ < 1024) ? (hid_bf + k0_)                   \
                                            : (ti_bf + (k0_ - 1024));          \
    _Pragma("unroll")                                                          \
    for (int rd_ = 0; rd_ < 2; ++rd_)                                          \
      gll16(p_ + (size_t)(mbase + (h) * 128 + rd_ * 64 + srow8) * HD + scol,   \
            lds + (bsel) * 32768 + (h) * 8192 + rd_ * 4096 + w * 512);         \
  } while (0)

#define STAGE_B(s, bsel, h) do {                                               \
    const int k0_ = (s) * 64;                                                  \
    _Pragma("unroll")                                                          \
    for (int rd_ = 0; rd_ < 2; ++rd_)                                          \
      gll16(Wt_bf + (size_t)(nbase + (h) * 128 + rd_ * 64 + srow8) * FF        \
                  + k0_ + scol,                                                \
            lds + (bsel) * 32768 + 16384 + (h) * 8192 + rd_ * 4096 + w * 512); \
  } while (0)

#define PH_MID do {                                                            \
    __builtin_amdgcn_s_setprio(1);                                             \
  } while (0)

#define PH_END do {                                                            \
    __builtin_amdgcn_s_setprio(0);                                             \
    __builtin_amdgcn_sched_barrier(0);                                         \
    __builtin_amdgcn_s_barrier();                                              \
  } while (0)

  f32x4 acc[8][4] = {};
  bf16x8 aR[4][2], bR[4][2];

  // prologue: A0,A1,B0,B1(tile0); B0,B1(tile1). vmcnt(4) -> tile0 landed.
  STAGE_A(0, 0, 0); STAGE_A(0, 0, 1);
  STAGE_B(0, 0, 0); STAGE_B(0, 0, 1);
  STAGE_B(1, 1, 0); STAGE_B(1, 1, 1);
  asm volatile("s_waitcnt vmcnt(4)" ::: "memory");
  __builtin_amdgcn_sched_barrier(0);
  __builtin_amdgcn_s_barrier();

#define TILE(tt, c) do {                                                       \
    const int sa_ = ((tt) + 1 > 31) ? 31 : (tt) + 1;                           \
    const int sb_ = ((tt) + 2 > 31) ? 31 : (tt) + 2;                           \
    const int abase_ = (c) * 32768 + wm * 8192 + lrow * 64;                    \
    const int bbase_ = (c) * 32768 + 16384 + (wn >> 1) * 8192                  \
                       + ((wn & 1) * 64 + lrow) * 64;                          \
    /* ---- P0: a[0..3], b[0..1]; stage A0(tt+1); MFMA m0-3 x n0-1 ---- */     \
    _Pragma("unroll")                                                          \
    for (int m_ = 0; m_ < 4; ++m_) {                                           \
      aR[m_][0] = *(const bf16x8*)(lds + abase_ + m_ * 1024 + ck0);            \
      aR[m_][1] = *(const bf16x8*)(lds + abase_ + m_ * 1024 + ck1);            \
    }                                                                          \
    _Pragma("unroll")                                                          \
    for (int n_ = 0; n_ < 2; ++n_) {                                           \
      bR[n_][0] = *(const bf16x8*)(lds + bbase_ + n_ * 1024 + ck0);            \
      bR[n_][1] = *(const bf16x8*)(lds + bbase_ + n_ * 1024 + ck1);            \
    }                                                                          \
    STAGE_A(sa_, 1 - (c), 0);                                                  \
    PH_MID;                                                                    \
    _Pragma("unroll")                                                          \
    for (int m_ = 0; m_ < 4; ++m_)                                             \
      _Pragma("unroll")                                                        \
      for (int n_ = 0; n_ < 2; ++n_) {                                         \
        acc[m_][n_] = __builtin_amdgcn_mfma_f32_16x16x32_bf16(                 \
            aR[m_][0], bR[n_][0], acc[m_][n_], 0, 0, 0);                       \
        acc[m_][n_] = __builtin_amdgcn_mfma_f32_16x16x32_bf16(                 \
            aR[m_][1], bR[n_][1], acc[m_][n_], 0, 0, 0);                       \
      }                                                                        \
    PH_END;                                                                    \
    /* ---- P1: b[2..3]; stage A1(tt+1); MFMA m0-3 x n2-3 ---- */              \
    _Pragma("unroll")                                                          \
    for (int n_ = 2; n_ < 4; ++n_) {                                           \
      bR[n_][0] = *(const bf16x8*)(lds + bbase_ + n_ * 1024 + ck0);            \
      bR[n_][1] = *(const bf16x8*)(lds + bbase_ + n_ * 1024 + ck1);            \
    }                                                                          \
    STAGE_A(sa_, 1 - (c), 1);                                                  \
    PH_MID;                                                                    \
    _Pragma("unroll")                                                          \
    for (int m_ = 0; m_ < 4; ++m_)                                             \
      _Pragma("unroll")                                                        \
      for (int n_ = 2; n_ < 4; ++n_) {                                         \
        acc[m_][n_] = __builtin_amdgcn_mfma_f32_16x16x32_bf16(                 \
            aR[m_][0], bR[n_][0], acc[m_][n_], 0, 0, 0);                       \
        acc[m_][n_] = __builtin_amdgcn_mfma_f32_16x16x32_bf16(                 \
            aR[m_][1], bR[n_][1], acc[m_][n_], 0, 0, 0);                       \
      }                                                                        \
    PH_END;                                                                    \
    /* ---- P2: a[4..7] (reuse regs); stage B0(tt+2); MFMA m4-7 x n0-1 ---- */ \
    _Pragma("unroll")                                                          \
    for (int m_ = 0; m_ < 4; ++m_) {                                           \
      aR[m_][0] = *(const bf16x8*)(lds + abase_ + (m_ + 4) * 1024 + ck0);      \
      aR[m_][1] = *(const bf16x8*)(lds + abase_ + (m_ + 4) * 1024 + ck1);      \
    }                                                                          \
    STAGE_B(sb_, (c), 0);                                                      \
    PH_MID;                                                                    \
    _Pragma("unroll")                                                          \
    for (int m_ = 0; m_ < 4; ++m_)                                             \
      _Pragma("unroll")                                                        \
      for (int n_ = 0; n_ < 2; ++n_) {                                         \
        acc[m_ + 4][n_] = __builtin_amdgcn_mfma_f32_16x16x32_bf16(             \
            aR[m_][0], bR[n_][0], acc[m_ + 4][n_], 0, 0, 0);                   \
        acc[m_ + 4][n_] = __builtin_amdgcn_mfma_f32_16x16x32_bf16(             \
            aR[m_][1], bR[n_][1], acc[m_ + 4][n_], 0, 0, 0);                   \
      }                                                                        \
    PH_END;                                                                    \
    /* ---- P3: no reads; stage B1(tt+2); MFMA m4-7 x n2-3; vmcnt(4) ---- */   \
    STAGE_B(sb_, (c), 1);                                                      \
    PH_MID;                                                                    \
    _Pragma("unroll")                                                          \
    for (int m_ = 0; m_ < 4; ++m_)                                             \
      _Pragma("unroll")                                                        \
      for (int n_ = 2; n_ < 4; ++n_) {                                         \
        acc[m_ + 4][n_] = __builtin_amdgcn_mfma_f32_16x16x32_bf16(             \
            aR[m_][0], bR[n_][0], acc[m_ + 4][n_], 0, 0, 0);                   \
        acc[m_ + 4][n_] = __builtin_amdgcn_mfma_f32_16x16x32_bf16(             \
            aR[m_][1], bR[n_][1], acc[m_ + 4][n_], 0, 0, 0);                   \
      }                                                                        \
    __builtin_amdgcn_s_setprio(0);                                             \
    asm volatile("s_waitcnt vmcnt(4)" ::: "memory");                           \
    __builtin_amdgcn_sched_barrier(0);                                         \
    __builtin_amdgcn_s_barrier();                                              \
  } while (0)

  for (int tt = 0; tt < 32; tt += 2) {
    TILE(tt, 0);
    TILE(tt + 1, 1);
  }
#undef TILE
#undef PH_MID
#undef PH_END
#undef STAGE_A
#undef STAGE_B

  // epilogue: tanh + bias + bf16 residual (hid_bf L2-warm from staging)
#pragma unroll
  for (int m = 0; m < 8; ++m) {
    const int row = mbase + wm * 128 + m * 16 + lk * 4;
#pragma unroll
    for (int n = 0; n < 4; ++n) {
      const int col = nbase + wn * 64 + n * 16 + lrow;
      const float bv = bias[col];
#pragma unroll
      for (int j = 0; j < 4; ++j) {
        float x = acc[m][n][j] + bv;
        float xc = fminf(fmaxf(x, -15.f), 15.f);
        float e2 = __expf(2.f * xc);
        float th = (e2 - 1.f) / (e2 + 1.f);
        size_t oi = (size_t)(row + j) * HD + col;
        unsigned int u = ((unsigned int)hid_bf[oi]) << 16;
        out[oi] = th + __builtin_bit_cast(float, u);
      }
    }
  }
}

// ---------------------------------------------------------------- launch
extern "C" void kernel_launch(void* const* d_in, const int* in_sizes, int n_in,
                              void* d_out, int out_size, void* d_ws, size_t ws_size,
                              hipStream_t stream) {
  const float* tgt  = (const float*)d_in[0];  // (B,T,2H)
  const float* hid  = (const float*)d_in[1];  // (B,S,2H)
  const float* W    = (const float*)d_in[2];  // (4H,2H)
  const float* bias = (const float*)d_in[3];  // (2H,)
  float* out = (float*)d_out;

  char* ws = (char*)d_ws;
  unsigned short* hid_bf  = (unsigned short*)(ws);                    //  64 MiB
  unsigned short* ti_bf   = (unsigned short*)(ws + 67108864);         //  64 MiB
  unsigned short* tgt_bf  = (unsigned short*)(ws + 134217728);        //   4 MiB
  unsigned short* tgtT_bf = (unsigned short*)(ws + 138412032);        //   4 MiB
  unsigned short* Wt_bf   = (unsigned short*)(ws + 142606336);        //   4 MiB

  cvt_bf16_kernel<<<512, 256, 0, stream>>>(tgt, tgt_bf, (BB * TT * HD) / 4);
  tcvt_kernel<<<dim3(HD / 32, TT / 32, BB), dim3(32, 8), 0, stream>>>(tgt, tgtT_bf, TT, HD);
  tcvt_kernel<<<dim3(HD / 32, FF / 32, 1), dim3(32, 8), 0, stream>>>(W, Wt_bf, FF, HD);
  attn_kernel<<<dim3(SS / 64, BB), 256, 0, stream>>>(hid, hid_bf, tgt_bf, tgtT_bf, ti_bf);
  gemm_kernel<<<dim3(HD / 128 / 2, MM / 256), 512, 0, stream>>>(hid_bf, ti_bf, Wt_bf, bias, out);
}

// Round 9
// 208.235 us; speedup vs baseline: 1.1940x; 1.1940x over previous
//
#include <hip/hip_runtime.h>
#include <hip/hip_bf16.h>

// Problem constants
#define BB 32
#define SS 1024
#define TT 64
#define HD 1024   // 2H
#define FF 2048   // 4H
#define MM (BB*SS) // 32768

typedef __attribute__((ext_vector_type(4))) float f32x4;
typedef __attribute__((ext_vector_type(8))) short bf16x8;
typedef __attribute__((ext_vector_type(8))) unsigned short u16x8;

__device__ __forceinline__ unsigned short f2bf(float f) {
  __hip_bfloat16 h = __float2bfloat16(f);
  return __builtin_bit_cast(unsigned short, h);
}

__device__ __forceinline__ void gll16(const void* g, void* l) {
  __builtin_amdgcn_global_load_lds(
      (const __attribute__((address_space(1))) void*)g,
      (__attribute__((address_space(3))) void*)l, 16, 0, 0);
}

// ---------------------------------------------------------------- converts
__global__ void cvt_bf16_kernel(const float* __restrict__ x,
                                unsigned short* __restrict__ y, int n4) {
  int stride = gridDim.x * blockDim.x;
  for (int i = blockIdx.x * blockDim.x + threadIdx.x; i < n4; i += stride) {
    float4 v = reinterpret_cast<const float4*>(x)[i];
    ushort4 o;
    o.x = f2bf(v.x); o.y = f2bf(v.y); o.z = f2bf(v.z); o.w = f2bf(v.w);
    reinterpret_cast<ushort4*>(y)[i] = o;
  }
}

// transpose+convert: in fp32 [R][C] -> out bf16 [C][R]   (W: 2048x1024 -> 1024x2048)
__global__ void tcvt_kernel(const float* __restrict__ in,
                            unsigned short* __restrict__ out, int R, int C) {
  __shared__ float tile[32][33];
  const float* ip = in;
  unsigned short* op = out;
  const int c0 = blockIdx.x * 32, r0 = blockIdx.y * 32;
  const int tx = threadIdx.x, ty = threadIdx.y; // (32, 8)
#pragma unroll
  for (int j = 0; j < 4; ++j)
    tile[ty + j * 8][tx] = ip[(size_t)(r0 + ty + j * 8) * C + c0 + tx];
  __syncthreads();
#pragma unroll
  for (int j = 0; j < 4; ++j)
    op[(size_t)(c0 + ty + j * 8) * R + r0 + tx] = f2bf(tile[tx][ty + j * 8]);
}

// ---------------------------------------------------------------- U = tgt @ W2
// U[b][t][d] = sum_k tgt[b][t][k] * W[1024+k][d]; stored TRANSPOSED as
// Ut[b][d][t] (bf16) so the main gemm can stage it as a stride-64 B-tile.
// grid (16 nblocks of 64 d, 32 b), 256 thr. W2 n-major slice of Wt_bf is
// L2-resident (2 MB); reads per-lane direct (same proven pattern as QK^T).
__global__ __launch_bounds__(256) void u_kernel(
    const unsigned short* __restrict__ tgt_bf,  // [B][T][1024]
    const unsigned short* __restrict__ Wt_bf,   // [1024 d][2048 f]
    unsigned short* __restrict__ Ut)            // [B][1024 d][64 t]
{
  const int tid = threadIdx.x;
  const int w = tid >> 6, l = tid & 63;
  const int lrow = l & 15, lk = l >> 4;
  const int nb = blockIdx.x * 64;   // d base
  const int b = blockIdx.y;

  const unsigned short* ap = tgt_bf + (size_t)b * TT * HD
                             + (size_t)(w * 16 + lrow) * HD + lk * 8;
  const unsigned short* wp = Wt_bf + (size_t)(nb + lrow) * FF + 1024 + lk * 8;

  f32x4 acc[4] = {};
  for (int kt = 0; kt < 32; ++kt) {
    const int kk = kt * 32;
    bf16x8 a = *reinterpret_cast<const bf16x8*>(ap + kk);
#pragma unroll
    for (int ct = 0; ct < 4; ++ct) {
      bf16x8 bb = *reinterpret_cast<const bf16x8*>(wp + (size_t)ct * 16 * FF + kk);
      acc[ct] = __builtin_amdgcn_mfma_f32_16x16x32_bf16(a, bb, acc[ct], 0, 0, 0);
    }
  }
  unsigned short* up = Ut + (size_t)b * HD * TT;
#pragma unroll
  for (int ct = 0; ct < 4; ++ct)
#pragma unroll
    for (int j = 0; j < 4; ++j)
      up[(size_t)(nb + ct * 16 + lrow) * TT + (w * 16 + lk * 4 + j)] = f2bf(acc[ct][j]);
}

// ---------------------------------------------------------------- attention
// QK^T + softmax only (PV folded into the main gemm via P@(tgt.W2)).
// Barrier-free, no LDS: per-lane direct Q loads from hid fp32 (read once,
// converted in-reg; bf16 chunk stored as hid_bf side output) and K from
// L2-resident tgt_bf. Writes P bf16 (B,S,64) = 4 MB.
__global__ __launch_bounds__(256) void attn_kernel(
    const float* __restrict__ hid_f32,           // [B][S][D] fp32
    unsigned short* __restrict__ hid_bf,         // out: [B][S][D] bf16
    const unsigned short* __restrict__ tgt_bf,   // [B][T][D]
    unsigned short* __restrict__ P_bf)           // out: [M][64]
{
  const int tid = threadIdx.x;
  const int w = tid >> 6, l = tid & 63;
  const int lrow = l & 15, lk = l >> 4;
  const int b = blockIdx.y;
  const int sbase = blockIdx.x * 64;
  const size_t hbase = ((size_t)b * SS + sbase) * HD;

  const int qrow = w * 16 + lrow;
  const float* qp = hid_f32 + hbase + (size_t)qrow * HD + lk * 8;
  unsigned short* qbf = hid_bf + hbase + (size_t)qrow * HD + lk * 8;
  const unsigned short* kp = tgt_bf + (size_t)b * TT * HD + (size_t)lrow * HD + lk * 8;

  f32x4 accs[4] = {};
  for (int kt = 0; kt < 32; ++kt) {
    const int kk = kt * 32;
    float4 f0 = *reinterpret_cast<const float4*>(qp + kk);
    float4 f1 = *reinterpret_cast<const float4*>(qp + kk + 4);
    bf16x8 a;
    a[0] = (short)f2bf(f0.x); a[1] = (short)f2bf(f0.y);
    a[2] = (short)f2bf(f0.z); a[3] = (short)f2bf(f0.w);
    a[4] = (short)f2bf(f1.x); a[5] = (short)f2bf(f1.y);
    a[6] = (short)f2bf(f1.z); a[7] = (short)f2bf(f1.w);
    *reinterpret_cast<bf16x8*>(qbf + kk) = a;   // hid_bf side output
#pragma unroll
    for (int ct = 0; ct < 4; ++ct) {
      bf16x8 bb = *reinterpret_cast<const bf16x8*>(kp + (size_t)ct * 16 * HD + kk);
      accs[ct] = __builtin_amdgcn_mfma_f32_16x16x32_bf16(a, bb, accs[ct], 0, 0, 0);
    }
  }

  // softmax over t (lane holds q-rows lk*4+j, t-cols ct*16+lrow)
  float p[4][4];
#pragma unroll
  for (int j = 0; j < 4; ++j) {
    float mx = fmaxf(fmaxf(accs[0][j], accs[1][j]), fmaxf(accs[2][j], accs[3][j]));
#pragma unroll
    for (int d = 1; d < 16; d <<= 1) mx = fmaxf(mx, __shfl_xor(mx, d, 64));
    float sum = 0.f;
#pragma unroll
    for (int ct = 0; ct < 4; ++ct) { p[ct][j] = __expf(accs[ct][j] - mx); sum += p[ct][j]; }
#pragma unroll
    for (int d = 1; d < 16; d <<= 1) sum += __shfl_xor(sum, d, 64);
    float inv = 1.f / sum;
#pragma unroll
    for (int ct = 0; ct < 4; ++ct) p[ct][j] *= inv;
  }
#pragma unroll
  for (int j = 0; j < 4; ++j) {
    const size_t prow = ((size_t)b * SS + sbase + w * 16 + lk * 4 + j) * TT;
#pragma unroll
    for (int ct = 0; ct < 4; ++ct)
      P_bf[prow + ct * 16 + lrow] = f2bf(p[ct][j]);
  }
}

// ---------------------------------------------------------------- transform GEMM
// out = tanh(hid.W1 + P.U + b) + hid.  K = 1024 (hid x W1) + 64 (P x Ut[b]).
// R7 schedule (measured 150us/912TF at K=2048, 0 conflicts): 256x256 / BK=64 /
// 8 waves / 16x16x32 MFMA / 4 phase-end barriers / 3-bit XOR swizzle /
// counted vmcnt(4); 17 tiles, last tile issues dead stages + vmcnt(0).

__global__ __launch_bounds__(512) void gemm_kernel(
    const unsigned short* __restrict__ hid_bf,  // [M][1024]
    const unsigned short* __restrict__ P_bf,    // [M][64]
    const unsigned short* __restrict__ Wt_bf,   // [1024][2048]  (n-major)
    const unsigned short* __restrict__ Ut,      // [B][1024][64]
    const float* __restrict__ bias,             // [1024]
    float* __restrict__ out)                    // [M][1024]
{
  __shared__ unsigned short lds[65536];  // 128 KiB

  const int tid = threadIdx.x;
  const int w = tid >> 6, l = tid & 63;
  const int wm = w >> 2, wn = w & 3;       // 2 x 4 wave grid
  const int lrow = l & 15, lk = l >> 4;

  // XCD-aware bijective swizzle (nwg = 512, divisible by 8)
  const int orig = blockIdx.y * 4 + blockIdx.x;
  const int lid = (orig & 7) * 64 + (orig >> 3);
  const int nbase = (lid & 3) * 256;
  const int mbase = (lid >> 2) * 256;
  const int bidx = mbase >> 10;            // batch of this block's rows

  const int srow8 = w * 8 + (l >> 3);           // 0..63
  const int scol = ((l & 7) ^ (l >> 3)) << 3;   // pre-swizzled col chunk

  const int ck0 = ((lk)     ^ (lrow & 7)) << 3;
  const int ck1 = ((4 + lk) ^ (lrow & 7)) << 3;

#define STAGE_A(s, bsel, h) do {                                               \
    const unsigned short* p_; size_t str_;                                     \
    if ((s) < 16) { p_ = hid_bf + (s) * 64; str_ = 1024; }                     \
    else          { p_ = P_bf;              str_ = 64;   }                     \
    _Pragma("unroll")                                                          \
    for (int rd_ = 0; rd_ < 2; ++rd_)                                          \
      gll16(p_ + (size_t)(mbase + (h) * 128 + rd_ * 64 + srow8) * str_ + scol, \
            lds + (bsel) * 32768 + (h) * 8192 + rd_ * 4096 + w * 512);         \
  } while (0)

#define STAGE_B(s, bsel, h) do {                                               \
    const unsigned short* p_; size_t str_;                                     \
    if ((s) < 16) { p_ = Wt_bf + (s) * 64;               str_ = 2048; }        \
    else          { p_ = Ut + (size_t)bidx * HD * TT;    str_ = 64;   }        \
    _Pragma("unroll")                                                          \
    for (int rd_ = 0; rd_ < 2; ++rd_)                                          \
      gll16(p_ + (size_t)(nbase + (h) * 128 + rd_ * 64 + srow8) * str_ + scol, \
            lds + (bsel) * 32768 + 16384 + (h) * 8192 + rd_ * 4096 + w * 512); \
  } while (0)

#define PH_MID do { __builtin_amdgcn_s_setprio(1); } while (0)
#define PH_END do {                                                            \
    __builtin_amdgcn_s_setprio(0);                                             \
    __builtin_amdgcn_sched_barrier(0);                                         \
    __builtin_amdgcn_s_barrier();                                              \
  } while (0)

  f32x4 acc[8][4] = {};
  bf16x8 aR[4][2], bR[4][2];

  // prologue: A0,A1,B0,B1(tile0); B0,B1(tile1). vmcnt(4) -> tile0 landed.
  STAGE_A(0, 0, 0); STAGE_A(0, 0, 1);
  STAGE_B(0, 0, 0); STAGE_B(0, 0, 1);
  STAGE_B(1, 1, 0); STAGE_B(1, 1, 1);
  asm volatile("s_waitcnt vmcnt(4)" ::: "memory");
  __builtin_amdgcn_sched_barrier(0);
  __builtin_amdgcn_s_barrier();

#define TILE(tt, c, last) do {                                                 \
    const int sa_ = ((tt) + 1 > 16) ? 16 : (tt) + 1;                           \
    const int sb_ = ((tt) + 2 > 16) ? 16 : (tt) + 2;                           \
    const int abase_ = (c) * 32768 + wm * 8192 + lrow * 64;                    \
    const int bbase_ = (c) * 32768 + 16384 + (wn >> 1) * 8192                  \
                       + ((wn & 1) * 64 + lrow) * 64;                          \
    /* ---- P0: a[0..3], b[0..1]; stage A0(sa); MFMA m0-3 x n0-1 ---- */       \
    _Pragma("unroll")                                                          \
    for (int m_ = 0; m_ < 4; ++m_) {                                           \
      aR[m_][0] = *(const bf16x8*)(lds + abase_ + m_ * 1024 + ck0);            \
      aR[m_][1] = *(const bf16x8*)(lds + abase_ + m_ * 1024 + ck1);            \
    }                                                                          \
    _Pragma("unroll")                                                          \
    for (int n_ = 0; n_ < 2; ++n_) {                                           \
      bR[n_][0] = *(const bf16x8*)(lds + bbase_ + n_ * 1024 + ck0);            \
      bR[n_][1] = *(const bf16x8*)(lds + bbase_ + n_ * 1024 + ck1);            \
    }                                                                          \
    STAGE_A(sa_, 1 - (c), 0);                                                  \
    PH_MID;                                                                    \
    _Pragma("unroll")                                                          \
    for (int m_ = 0; m_ < 4; ++m_)                                             \
      _Pragma("unroll")                                                        \
      for (int n_ = 0; n_ < 2; ++n_) {                                         \
        acc[m_][n_] = __builtin_amdgcn_mfma_f32_16x16x32_bf16(                 \
            aR[m_][0], bR[n_][0], acc[m_][n_], 0, 0, 0);                       \
        acc[m_][n_] = __builtin_amdgcn_mfma_f32_16x16x32_bf16(                 \
            aR[m_][1], bR[n_][1], acc[m_][n_], 0, 0, 0);                       \
      }                                                                        \
    PH_END;                                                                    \
    /* ---- P1: b[2..3]; stage A1(sa); MFMA m0-3 x n2-3 ---- */                \
    _Pragma("unroll")                                                          \
    for (int n_ = 2; n_ < 4; ++n_) {                                           \
      bR[n_][0] = *(const bf16x8*)(lds + bbase_ + n_ * 1024 + ck0);            \
      bR[n_][1] = *(const bf16x8*)(lds + bbase_ + n_ * 1024 + ck1);            \
    }                                                                          \
    STAGE_A(sa_, 1 - (c), 1);                                                  \
    PH_MID;                                                                    \
    _Pragma("unroll")                                                          \
    for (int m_ = 0; m_ < 4; ++m_)                                             \
      _Pragma("unroll")                                                        \
      for (int n_ = 2; n_ < 4; ++n_) {                                         \
        acc[m_][n_] = __builtin_amdgcn_mfma_f32_16x16x32_bf16(                 \
            aR[m_][0], bR[n_][0], acc[m_][n_], 0, 0, 0);                       \
        acc[m_][n_] = __builtin_amdgcn_mfma_f32_16x16x32_bf16(                 \
            aR[m_][1], bR[n_][1], acc[m_][n_], 0, 0, 0);                       \
      }                                                                        \
    PH_END;                                                                    \
    /* ---- P2: a[4..7]; stage B0(sb); MFMA m4-7 x n0-1 ---- */                \
    _Pragma("unroll")                                                          \
    for (int m_ = 0; m_ < 4; ++m_) {                                           \
      aR[m_][0] = *(const bf16x8*)(lds + abase_ + (m_ + 4) * 1024 + ck0);      \
      aR[m_][1] = *(const bf16x8*)(lds + abase_ + (m_ + 4) * 1024 + ck1);      \
    }                                                                          \
    STAGE_B(sb_, (c), 0);                                                      \
    PH_MID;                                                                    \
    _Pragma("unroll")                                                          \
    for (int m_ = 0; m_ < 4; ++m_)                                             \
      _Pragma("unroll")                                                        \
      for (int n_ = 0; n_ < 2; ++n_) {                                         \
        acc[m_ + 4][n_] = __builtin_amdgcn_mfma_f32_16x16x32_bf16(             \
            aR[m_][0], bR[n_][0], acc[m_ + 4][n_], 0, 0, 0);                   \
        acc[m_ + 4][n_] = __builtin_amdgcn_mfma_f32_16x16x32_bf16(             \
            aR[m_][1], bR[n_][1], acc[m_ + 4][n_], 0, 0, 0);                   \
      }                                                                        \
    PH_END;                                                                    \
    /* ---- P3: stage B1(sb); MFMA m4-7 x n2-3; vmcnt ---- */                  \
    STAGE_B(sb_, (c), 1);                                                      \
    PH_MID;                                                                    \
    _Pragma("unroll")                                                          \
    for (int m_ = 0; m_ < 4; ++m_)                                             \
      _Pragma("unroll")                                                        \
      for (int n_ = 2; n_ < 4; ++n_) {                                         \
        acc[m_ + 4][n_] = __builtin_amdgcn_mfma_f32_16x16x32_bf16(             \
            aR[m_][0], bR[n_][0], acc[m_ + 4][n_], 0, 0, 0);                   \
        acc[m_ + 4][n_] = __builtin_amdgcn_mfma_f32_16x16x32_bf16(             \
            aR[m_][1], bR[n_][1], acc[m_ + 4][n_], 0, 0, 0);                   \
      }                                                                        \
    __builtin_amdgcn_s_setprio(0);                                             \
    if (last) { asm volatile("s_waitcnt vmcnt(0)" ::: "memory"); }             \
    else      { asm volatile("s_waitcnt vmcnt(4)" ::: "memory"); }             \
    __builtin_amdgcn_sched_barrier(0);                                         \
    __builtin_amdgcn_s_barrier();                                              \
  } while (0)

  for (int tt = 0; tt < 16; tt += 2) {
    TILE(tt, 0, false);
    TILE(tt + 1, 1, false);
  }
  TILE(16, 0, true);   // P x Ut[b] tile (dead stages keep vmcnt uniform)
#undef TILE
#undef PH_MID
#undef PH_END
#undef STAGE_A
#undef STAGE_B

  // epilogue: tanh + bias + bf16 residual (hid_bf L2-warm from staging)
#pragma unroll
  for (int m = 0; m < 8; ++m) {
    const int row = mbase + wm * 128 + m * 16 + lk * 4;
#pragma unroll
    for (int n = 0; n < 4; ++n) {
      const int col = nbase + wn * 64 + n * 16 + lrow;
      const float bv = bias[col];
#pragma unroll
      for (int j = 0; j < 4; ++j) {
        float x = acc[m][n][j] + bv;
        float xc = fminf(fmaxf(x, -15.f), 15.f);
        float e2 = __expf(2.f * xc);
        float th = (e2 - 1.f) / (e2 + 1.f);
        size_t oi = (size_t)(row + j) * HD + col;
        unsigned int u = ((unsigned int)hid_bf[oi]) << 16;
        out[oi] = th + __builtin_bit_cast(float, u);
      }
    }
  }
}

// ---------------------------------------------------------------- launch
extern "C" void kernel_launch(void* const* d_in, const int* in_sizes, int n_in,
                              void* d_out, int out_size, void* d_ws, size_t ws_size,
                              hipStream_t stream) {
  const float* tgt  = (const float*)d_in[0];  // (B,T,2H)
  const float* hid  = (const float*)d_in[1];  // (B,S,2H)
  const float* W    = (const float*)d_in[2];  // (4H,2H)
  const float* bias = (const float*)d_in[3];  // (2H,)
  float* out = (float*)d_out;

  char* ws = (char*)d_ws;
  unsigned short* hid_bf = (unsigned short*)(ws);                //  64 MiB
  unsigned short* tgt_bf = (unsigned short*)(ws + 67108864);     //   4 MiB
  unsigned short* Wt_bf  = (unsigned short*)(ws + 71303168);     //   4 MiB
  unsigned short* P_bf   = (unsigned short*)(ws + 75497472);     //   4 MiB
  unsigned short* Ut     = (unsigned short*)(ws + 79691776);     //   4 MiB

  cvt_bf16_kernel<<<512, 256, 0, stream>>>(tgt, tgt_bf, (BB * TT * HD) / 4);
  tcvt_kernel<<<dim3(HD / 32, FF / 32), dim3(32, 8), 0, stream>>>(W, Wt_bf, FF, HD);
  u_kernel<<<dim3(HD / 64, BB), 256, 0, stream>>>(tgt_bf, Wt_bf, Ut);
  attn_kernel<<<dim3(SS / 64, BB), 256, 0, stream>>>(hid, hid_bf, tgt_bf, P_bf);
  gemm_kernel<<<dim3(HD / 128 / 2, MM / 256), 512, 0, stream>>>(hid_bf, P_bf, Wt_bf, Ut, bias, out);
}